// Round 16
// baseline (726.416 us; speedup 1.0000x reference)
//
#include <hip/hip_runtime.h>
#include <cstdint>
#include <math.h>

// GREEN since r6. Best r15 = 489us. Coherent model (r15): 2 waves/SIMD truly
// resident (OccupancyPercent 11.8 is a gfx94x-formula artifact), wall 4075
// cyc/SIMD-step, VALU issue ~2x1200 cyc = 59% = measured VALUBusy -> genuinely
// VALU-issue-bound; dominant class = 384 scalar v_fma_f32/wave-step.
// THIS ROUND: packed f32 dot. gfx950 v_pk_fma_f32 does 2 FMAs/instr (only
// path to the 157TF f32 peak; m07 scalar ceiling ~103TF). Chains a/b are
// already float2 lo/hi pairs in hsh2 -> v2f accumulators + elementwise_fma
// with {u,u} broadcast: 384 -> 192 FMA instrs, ~-380 cyc/wave-step. Same IEEE
// fma per component, same values, same k-order -> bit-identical decisions.
// Everything else frozen at r15 (swizzled-b128 Un, diff-dense tail, fast
// transcendentals, sw-pipelined step).
// LESSONS: r13/r14 - moving DS work to VALU loses; only deletions win.
// EMPIRICAL RULES: only __launch_bounds__(64,1) gives the full reg budget;
// decisions rounding-robust (6 variants bit-identical); PRNG = partitionable
// threefry (key_t = tf((0,42),(0,t)); bits = o0^o1 of tf(key_t,(0,2s+cat)));
// f32 in/out; out = [4096*144][4096].

#define NSAMP 4096
#define NSTEP 144
#define HID 64
#define CPB 2            // chains per block (one wave)

typedef float v16f __attribute__((ext_vector_type(16)));
typedef float v2f  __attribute__((ext_vector_type(2)));
typedef float v4f  __attribute__((ext_vector_type(4)));

// ---- JAX threefry2x32 (20 rounds, key-inject every 4) ----
__device__ __forceinline__ void threefry2x32(uint32_t k0, uint32_t k1,
                                             uint32_t x0, uint32_t x1,
                                             uint32_t& o0, uint32_t& o1) {
  const uint32_t ks0 = k0, ks1 = k1, ks2 = k0 ^ k1 ^ 0x1BD11BDAu;
  x0 += ks0; x1 += ks1;
#define TF_ROUND(d) { x0 += x1; x1 = (x1 << (d)) | (x1 >> (32 - (d))); x1 ^= x0; }
  TF_ROUND(13) TF_ROUND(15) TF_ROUND(26) TF_ROUND(6)
  x0 += ks1; x1 += ks2 + 1u;
  TF_ROUND(17) TF_ROUND(29) TF_ROUND(16) TF_ROUND(24)
  x0 += ks2; x1 += ks0 + 2u;
  TF_ROUND(13) TF_ROUND(15) TF_ROUND(26) TF_ROUND(6)
  x0 += ks0; x1 += ks1 + 3u;
  TF_ROUND(17) TF_ROUND(29) TF_ROUND(16) TF_ROUND(24)
  x0 += ks1; x1 += ks2 + 4u;
  TF_ROUND(13) TF_ROUND(15) TF_ROUND(26) TF_ROUND(6)
  x0 += ks2; x1 += ks0 + 5u;
#undef TF_ROUND
  o0 = x0; o1 = x1;
}

// fast branch-free f32 transcendentals (raw v_exp_f32 / v_log_f32 / v_rcp_f32)
__device__ __forceinline__ float fsig(float x) {        // 1/(1+e^-x), stable
  return __builtin_amdgcn_rcpf(1.0f + __expf(-x));
}
__device__ __forceinline__ float ftanh(float x) {       // 1 - 2/(e^2x+1)
  const float e = __expf(2.0f * x);
  return 1.0f - 2.0f * __builtin_amdgcn_rcpf(e + 1.0f);
}

__global__ __launch_bounds__(64, 1) void vmc_kernel(
    const float* __restrict__ W, const float* __restrict__ U,
    const float* __restrict__ B, const float* __restrict__ Wd,
    const float* __restrict__ Bd, float* __restrict__ out) {
  const int j = threadIdx.x;           // hidden unit owned by this lane
  const int s_base = blockIdx.x * CPB; // first of 2 chains in this block

  __shared__ __align__(16) float2 hsh2[HID];      // h[unit] = {chain a, chain b}
  __shared__ __align__(16) float4 unT4[HID * 16]; // Un^T, XOR-swizzled chunks
  __shared__ uint2 kkeys[NSTEP];
  __shared__ float gsh[CPB * 2 * NSTEP];          // gumbels [c*288 + 2t + cat]

  // --- per-step keys: key_t = threefry((0,42),(0,t)) ---
#pragma unroll 1
  for (int t = j; t < NSTEP; t += HID) {
    uint32_t o0, o1;
    threefry2x32(0u, 42u, 0u, (uint32_t)t, o0, o1);
    kkeys[t].x = o0; kkeys[t].y = o1;
  }
  // --- stage Un^T: lane j owns row j (Un column j), chunk c = k/4,
  // swizzled index c^(j&15). Global reads coalesced across lanes. ---
#pragma unroll 4
  for (int c = 0; c < 16; ++c) {
    float4 v;
    v.x = U[(4*c + 0) * 192 + 128 + j];
    v.y = U[(4*c + 1) * 192 + 128 + j];
    v.z = U[(4*c + 2) * 192 + 128 + j];
    v.w = U[(4*c + 3) * 192 + 128 + j];
    unT4[j * 16 + (c ^ (j & 15))] = v;
  }
  hsh2[j] = float2{0.0f, 0.0f};
  __syncthreads();

  // --- gumbels: EXACT path kept (f64 libm, one-time): bits = o0^o1 of
  // tf(key_t,(0,2s+cat)); u = bitcast(bits>>9|0x3f800000)-1 clamped tiny ---
#pragma unroll 1
  for (int id = j; id < CPB * 2 * NSTEP; id += HID) {
    const int c = id / 288;
    const int idx = id - c * 288;
    const uint2 kt = kkeys[idx >> 1];
    const uint32_t i = 2u * (uint32_t)(s_base + c) + (uint32_t)(idx & 1);
    uint32_t o0, o1;
    threefry2x32(kt.x, kt.y, 0u, i, o0, o1);
    const uint32_t bits = o0 ^ o1;
    union { uint32_t u; float f; } cv; cv.u = (bits >> 9) | 0x3F800000u;
    float uf = cv.f - 1.0f;
    uf = fmaxf(uf, 1.17549435e-38f);
    const float inner = (float)log((double)uf);
    gsh[id] = -(float)log((double)(-inner));
  }
  __syncthreads();

  // --- Uz, Ur columns for unit j: register-resident (128 floats, proven) ---
  v16f uz0, uz1, uz2, uz3, ur0, ur1, ur2, ur3;
#define LOADB(v, r, off) \
  { _Pragma("unroll") for (int e = 0; e < 16; ++e) v[e] = U[((r)*16 + e)*192 + (off) + j]; }
  LOADB(uz0, 0, 0)   LOADB(uz1, 1, 0)   LOADB(uz2, 2, 0)   LOADB(uz3, 3, 0)
  LOADB(ur0, 0, 64)  LOADB(ur1, 1, 64)  LOADB(ur2, 2, 64)  LOADB(ur3, 3, 64)
#undef LOADB

  const float b1z = B[192 + j], b1r = B[256 + j], b1n = B[320 + j];
  const float b0z = B[j],       b0r = B[64 + j],  b0n = B[128 + j];
  const float xW0z = W[j]       + b0z, xW1z = W[192 + j] + b0z;
  const float xW0r = W[64 + j]  + b0r, xW1r = W[256 + j] + b0r;
  const float xW0n = W[128 + j] + b0n, xW1n = W[320 + j] + b0n;
  const float wdd = Wd[2*j + 1] - Wd[2*j];   // dense difference column
  const float bdd = Bd[1] - Bd[0];
  const int swz = j & 15;

  float ha = 0.0f, hb_ = 0.0f;
  float logPa = 0.0f, logPb = 0.0f;
  float axz = b0z, axr = b0r, axn = b0n;  // t=0: x=0 -> xm = b[0]
  float bxz = b0z, bxr = b0r, bxn = b0n;
  // loop-carried packed dot accumulators {chain a, chain b}; h_{-1}=0
  v2f accz = {0.f, 0.f}, accr = {0.f, 0.f}, accn = {0.f, 0.f};

  for (int t = 0; t < NSTEP; ++t) {
    // ---- gates from the PREVIOUS iteration's dot (software pipeline) ----
    {
      const float az = axz + (accz.x + b1z), ar = axr + (accr.x + b1r);
      const float zz = fsig(az), rr = fsig(ar);
      const float hh = ftanh(axn + rr * (accn.x + b1n));
      ha = zz * ha + (1.0f - zz) * hh;
    }
    {
      const float az = bxz + (accz.y + b1z), ar = bxr + (accr.y + b1r);
      const float zz = fsig(az), rr = fsig(ar);
      const float hh = ftanh(bxn + rr * (accn.y + b1n));
      hb_ = zz * hb_ + (1.0f - zz) * hh;
    }
    hsh2[j] = float2{ha, hb_};   // single wave: LDS ops in program order

    // ---- dense: single difference-reduction per chain (r14-proven) ----
    float da = ha * wdd, db = hb_ * wdd;
#pragma unroll
    for (int m = 1; m < 64; m <<= 1) {
      da += __shfl_xor(da, m, 64);
      db += __shfl_xor(db, m, 64);
    }
    int sma, smb;
    {
      const float d = da + bdd;
      const float p1 = fsig(d), p0 = fsig(-d);
      const float lp0 = __logf(1e-10f + p0);
      const float lp1 = __logf(1e-10f + p1);
      const float g0 = gsh[2*t], g1 = gsh[2*t + 1];
      sma = (lp1 + g1) > (lp0 + g0);
      logPa += sma ? lp1 : lp0;
      axz = sma ? xW1z : xW0z;
      axr = sma ? xW1r : xW0r;
      axn = sma ? xW1n : xW0n;
    }
    {
      const float d = db + bdd;
      const float p1 = fsig(d), p0 = fsig(-d);
      const float lp0 = __logf(1e-10f + p0);
      const float lp1 = __logf(1e-10f + p1);
      const float g0 = gsh[288 + 2*t], g1 = gsh[288 + 2*t + 1];
      smb = (lp1 + g1) > (lp0 + g0);
      logPb += smb ? lp1 : lp0;
      bxz = smb ? xW1z : xW0z;
      bxr = smb ? xW1r : xW0r;
      bxn = smb ? xW1n : xW0n;
    }
    if (j == 0) {
      out[(s_base + 0) * NSTEP + t] = sma ? 1.0f : 0.0f;
      out[(s_base + 1) * NSTEP + t] = smb ? 1.0f : 0.0f;
    }

    // ---- dot for NEXT step: hm = h_t @ U, k-ascending fma from 0, PACKED:
    // v2f acc = {chain a, chain b}; h pair comes straight from hsh2 (lo/hi of
    // the b128 load); U broadcast {u,u}. Same per-component IEEE fma, same
    // order as r15 -> bit-identical decisions. Target: v_pk_fma_f32 x192. ----
    accz = (v2f){0.f, 0.f}; accr = (v2f){0.f, 0.f}; accn = (v2f){0.f, 0.f};
#define PK(acc, hp, u) acc = __builtin_elementwise_fma(hp, (v2f){(u), (u)}, acc)
#define DOTC(uzv, urv, blk, cc) \
    { const int c_ = (blk)*4 + (cc); \
      const v4f hA = *(const v4f*)&hsh2[c_*4]; \
      const v4f hB = *(const v4f*)&hsh2[c_*4 + 2]; \
      const float4 uv = unT4[j*16 + (c_ ^ swz)]; \
      const int e_ = (cc)*4; \
      const v2f h0 = __builtin_shufflevector(hA, hA, 0, 1); \
      const v2f h1 = __builtin_shufflevector(hA, hA, 2, 3); \
      const v2f h2 = __builtin_shufflevector(hB, hB, 0, 1); \
      const v2f h3 = __builtin_shufflevector(hB, hB, 2, 3); \
      PK(accz, h0, uzv[e_+0]); PK(accr, h0, urv[e_+0]); PK(accn, h0, uv.x); \
      PK(accz, h1, uzv[e_+1]); PK(accr, h1, urv[e_+1]); PK(accn, h1, uv.y); \
      PK(accz, h2, uzv[e_+2]); PK(accr, h2, urv[e_+2]); PK(accn, h2, uv.z); \
      PK(accz, h3, uzv[e_+3]); PK(accr, h3, urv[e_+3]); PK(accn, h3, uv.w); }
#define DOTBLK(uzv, urv, blk) \
    DOTC(uzv, urv, blk, 0) DOTC(uzv, urv, blk, 1) DOTC(uzv, urv, blk, 2) DOTC(uzv, urv, blk, 3)
    DOTBLK(uz0, ur0, 0)
    DOTBLK(uz1, ur1, 1)
    DOTBLK(uz2, ur2, 2)
    DOTBLK(uz3, ur3, 3)
#undef DOTBLK
#undef DOTC
#undef PK
  }

  if (j == 0) {
    *(float2*)&out[NSAMP * NSTEP + s_base] = float2{logPa, logPb};
  }
}

extern "C" void kernel_launch(void* const* d_in, const int* in_sizes, int n_in,
                              void* d_out, int out_size, void* d_ws, size_t ws_size,
                              hipStream_t stream) {
  // inputs (setup_inputs order): nsamples(1), W(2x192), U(64x192), b(2x192),
  // Wd(64x2), bd(2) — float32
  const float* W  = (const float*)d_in[1];
  const float* U  = (const float*)d_in[2];
  const float* B  = (const float*)d_in[3];
  const float* Wd = (const float*)d_in[4];
  const float* Bd = (const float*)d_in[5];
  vmc_kernel<<<dim3(NSAMP / CPB), dim3(HID), 0, stream>>>(W, U, B, Wd, Bd, (float*)d_out);
}

// Round 17
// 495.136 us; speedup vs baseline: 1.4671x; 1.4671x over previous
//
#include <hip/hip_runtime.h>
#include <cstdint>
#include <math.h>

// GREEN since r6. Best r15 = 489us. r16 (v2f pk_fma) 726us REGRESSION: VGPR
// 132->212, VALUBusy 59->38 - packed pairs forced alignment+movs, longer
// stalls. THIRD confirmation: only deletions win (r13 readlane, r14 accvgpr,
// r16 pack all lost by adding data movement).
// THIS ROUND = r15 verbatim + two pure deletions:
//  (a) tail sigmoid pair from ONE exp: e=exp(-d); p1=rcp(1+e); p0=e*p1
//      (-2 exp, -2 rcp per wave-step; |d|<=~10 by weight norms, no overflow)
//  (b) gumbel pair loaded as one b64 (float2) instead of two b32 (-2 DS/step)
// Ulp-level perturbation only - decisions proven invariant across 6 variants.
// Model (r15): 2 waves/SIMD resident, VALU 59%, DS ~55% - latency-bound mixed
// regime. Wave count structurally pinned at 2048 (CPB=1 -> 3/SIMD uneven
// batches; CPB=4 -> 1/SIMD). No f32 MFMA on CDNA4; bf16-split MFMA costs more
// in layout shuffles than it saves.
// EMPIRICAL RULES: only __launch_bounds__(64,1) gives the full reg budget;
// OccupancyPercent counter is gfx94x fallback (untrustworthy); PRNG =
// partitionable threefry (key_t = tf((0,42),(0,t)); bits = o0^o1 of
// tf(key_t,(0,2s+cat))); f32 in/out; out = [4096*144][4096].

#define NSAMP 4096
#define NSTEP 144
#define HID 64
#define CPB 2            // chains per block (one wave)

typedef float v16f __attribute__((ext_vector_type(16)));

// ---- JAX threefry2x32 (20 rounds, key-inject every 4) ----
__device__ __forceinline__ void threefry2x32(uint32_t k0, uint32_t k1,
                                             uint32_t x0, uint32_t x1,
                                             uint32_t& o0, uint32_t& o1) {
  const uint32_t ks0 = k0, ks1 = k1, ks2 = k0 ^ k1 ^ 0x1BD11BDAu;
  x0 += ks0; x1 += ks1;
#define TF_ROUND(d) { x0 += x1; x1 = (x1 << (d)) | (x1 >> (32 - (d))); x1 ^= x0; }
  TF_ROUND(13) TF_ROUND(15) TF_ROUND(26) TF_ROUND(6)
  x0 += ks1; x1 += ks2 + 1u;
  TF_ROUND(17) TF_ROUND(29) TF_ROUND(16) TF_ROUND(24)
  x0 += ks2; x1 += ks0 + 2u;
  TF_ROUND(13) TF_ROUND(15) TF_ROUND(26) TF_ROUND(6)
  x0 += ks0; x1 += ks1 + 3u;
  TF_ROUND(17) TF_ROUND(29) TF_ROUND(16) TF_ROUND(24)
  x0 += ks1; x1 += ks2 + 4u;
  TF_ROUND(13) TF_ROUND(15) TF_ROUND(26) TF_ROUND(6)
  x0 += ks2; x1 += ks0 + 5u;
#undef TF_ROUND
  o0 = x0; o1 = x1;
}

// fast branch-free f32 transcendentals (raw v_exp_f32 / v_log_f32 / v_rcp_f32)
__device__ __forceinline__ float fsig(float x) {        // 1/(1+e^-x), stable
  return __builtin_amdgcn_rcpf(1.0f + __expf(-x));
}
__device__ __forceinline__ float ftanh(float x) {       // 1 - 2/(e^2x+1)
  const float e = __expf(2.0f * x);
  return 1.0f - 2.0f * __builtin_amdgcn_rcpf(e + 1.0f);
}

__global__ __launch_bounds__(64, 1) void vmc_kernel(
    const float* __restrict__ W, const float* __restrict__ U,
    const float* __restrict__ B, const float* __restrict__ Wd,
    const float* __restrict__ Bd, float* __restrict__ out) {
  const int j = threadIdx.x;           // hidden unit owned by this lane
  const int s_base = blockIdx.x * CPB; // first of 2 chains in this block

  __shared__ __align__(16) float2 hsh2[HID];      // h[unit] = {chain a, chain b}
  __shared__ __align__(16) float4 unT4[HID * 16]; // Un^T, XOR-swizzled chunks
  __shared__ uint2 kkeys[NSTEP];
  __shared__ __align__(8) float gsh[CPB * 2 * NSTEP]; // gumbels [c*288+2t+cat]

  // --- per-step keys: key_t = threefry((0,42),(0,t)) ---
#pragma unroll 1
  for (int t = j; t < NSTEP; t += HID) {
    uint32_t o0, o1;
    threefry2x32(0u, 42u, 0u, (uint32_t)t, o0, o1);
    kkeys[t].x = o0; kkeys[t].y = o1;
  }
  // --- stage Un^T: lane j owns row j (Un column j), chunk c = k/4,
  // swizzled index c^(j&15). Global reads coalesced across lanes. ---
#pragma unroll 4
  for (int c = 0; c < 16; ++c) {
    float4 v;
    v.x = U[(4*c + 0) * 192 + 128 + j];
    v.y = U[(4*c + 1) * 192 + 128 + j];
    v.z = U[(4*c + 2) * 192 + 128 + j];
    v.w = U[(4*c + 3) * 192 + 128 + j];
    unT4[j * 16 + (c ^ (j & 15))] = v;
  }
  hsh2[j] = float2{0.0f, 0.0f};
  __syncthreads();

  // --- gumbels: EXACT path kept (f64 libm, one-time): bits = o0^o1 of
  // tf(key_t,(0,2s+cat)); u = bitcast(bits>>9|0x3f800000)-1 clamped tiny ---
#pragma unroll 1
  for (int id = j; id < CPB * 2 * NSTEP; id += HID) {
    const int c = id / 288;
    const int idx = id - c * 288;
    const uint2 kt = kkeys[idx >> 1];
    const uint32_t i = 2u * (uint32_t)(s_base + c) + (uint32_t)(idx & 1);
    uint32_t o0, o1;
    threefry2x32(kt.x, kt.y, 0u, i, o0, o1);
    const uint32_t bits = o0 ^ o1;
    union { uint32_t u; float f; } cv; cv.u = (bits >> 9) | 0x3F800000u;
    float uf = cv.f - 1.0f;
    uf = fmaxf(uf, 1.17549435e-38f);
    const float inner = (float)log((double)uf);
    gsh[id] = -(float)log((double)(-inner));
  }
  __syncthreads();

  // --- Uz, Ur columns for unit j: register-resident (128 floats, proven) ---
  v16f uz0, uz1, uz2, uz3, ur0, ur1, ur2, ur3;
#define LOADB(v, r, off) \
  { _Pragma("unroll") for (int e = 0; e < 16; ++e) v[e] = U[((r)*16 + e)*192 + (off) + j]; }
  LOADB(uz0, 0, 0)   LOADB(uz1, 1, 0)   LOADB(uz2, 2, 0)   LOADB(uz3, 3, 0)
  LOADB(ur0, 0, 64)  LOADB(ur1, 1, 64)  LOADB(ur2, 2, 64)  LOADB(ur3, 3, 64)
#undef LOADB

  const float b1z = B[192 + j], b1r = B[256 + j], b1n = B[320 + j];
  const float b0z = B[j],       b0r = B[64 + j],  b0n = B[128 + j];
  const float xW0z = W[j]       + b0z, xW1z = W[192 + j] + b0z;
  const float xW0r = W[64 + j]  + b0r, xW1r = W[256 + j] + b0r;
  const float xW0n = W[128 + j] + b0n, xW1n = W[320 + j] + b0n;
  const float wdd = Wd[2*j + 1] - Wd[2*j];   // dense difference column
  const float bdd = Bd[1] - Bd[0];
  const int swz = j & 15;

  float ha = 0.0f, hb_ = 0.0f;
  float logPa = 0.0f, logPb = 0.0f;
  float axz = b0z, axr = b0r, axn = b0n;  // t=0: x=0 -> xm = b[0]
  float bxz = b0z, bxr = b0r, bxn = b0n;
  // loop-carried dot accumulators; h_{-1}=0 -> dot=0 for t=0
  float hza = 0.f, hzb = 0.f, hra = 0.f, hrb = 0.f, hna = 0.f, hnb = 0.f;

  for (int t = 0; t < NSTEP; ++t) {
    // ---- gates from the PREVIOUS iteration's dot (software pipeline) ----
    {
      const float az = axz + (hza + b1z), ar = axr + (hra + b1r);
      const float zz = fsig(az), rr = fsig(ar);
      const float hh = ftanh(axn + rr * (hna + b1n));
      ha = zz * ha + (1.0f - zz) * hh;
    }
    {
      const float az = bxz + (hzb + b1z), ar = bxr + (hrb + b1r);
      const float zz = fsig(az), rr = fsig(ar);
      const float hh = ftanh(bxn + rr * (hnb + b1n));
      hb_ = zz * hb_ + (1.0f - zz) * hh;
    }
    hsh2[j] = float2{ha, hb_};   // single wave: LDS ops in program order

    // ---- dense: single difference-reduction per chain (r14-proven) ----
    float da = ha * wdd, db = hb_ * wdd;
#pragma unroll
    for (int m = 1; m < 64; m <<= 1) {
      da += __shfl_xor(da, m, 64);
      db += __shfl_xor(db, m, 64);
    }
    int sma, smb;
    {
      const float d = da + bdd;
      const float e = __expf(-d);                      // one exp for the pair
      const float p1 = __builtin_amdgcn_rcpf(1.0f + e);
      const float lp1 = __logf(1e-10f + p1);
      const float lp0 = __logf(1e-10f + e * p1);       // p0 = e/(1+e)
      const float2 g = *(const float2*)&gsh[2*t];      // one b64 load
      sma = (lp1 + g.y) > (lp0 + g.x);
      logPa += sma ? lp1 : lp0;
      axz = sma ? xW1z : xW0z;
      axr = sma ? xW1r : xW0r;
      axn = sma ? xW1n : xW0n;
    }
    {
      const float d = db + bdd;
      const float e = __expf(-d);
      const float p1 = __builtin_amdgcn_rcpf(1.0f + e);
      const float lp1 = __logf(1e-10f + p1);
      const float lp0 = __logf(1e-10f + e * p1);
      const float2 g = *(const float2*)&gsh[288 + 2*t];
      smb = (lp1 + g.y) > (lp0 + g.x);
      logPb += smb ? lp1 : lp0;
      bxz = smb ? xW1z : xW0z;
      bxr = smb ? xW1r : xW0r;
      bxn = smb ? xW1n : xW0n;
    }
    if (j == 0) {
      out[(s_base + 0) * NSTEP + t] = sma ? 1.0f : 0.0f;
      out[(s_base + 1) * NSTEP + t] = smb ? 1.0f : 0.0f;
    }

    // ---- dot for NEXT step: hm = h_t @ U, k-ascending FMA from 0.
    // h via uniform b128 broadcast; Un via swizzled per-lane b128 rows.
    // (r15 form verbatim - bit-identical decisions) ----
    hza = 0.f; hzb = 0.f; hra = 0.f; hrb = 0.f; hna = 0.f; hnb = 0.f;
#define DOTC(uzv, urv, blk, cc) \
    { const int c_ = (blk)*4 + (cc); \
      const float4 hA = *(const float4*)&hsh2[c_*4]; \
      const float4 hB = *(const float4*)&hsh2[c_*4 + 2]; \
      const float4 uv = unT4[j*16 + (c_ ^ swz)]; \
      const int e_ = (cc)*4; \
      hza = __builtin_fmaf(hA.x, uzv[e_+0], hza); hzb = __builtin_fmaf(hA.y, uzv[e_+0], hzb); \
      hra = __builtin_fmaf(hA.x, urv[e_+0], hra); hrb = __builtin_fmaf(hA.y, urv[e_+0], hrb); \
      hna = __builtin_fmaf(hA.x, uv.x,      hna); hnb = __builtin_fmaf(hA.y, uv.x,      hnb); \
      hza = __builtin_fmaf(hA.z, uzv[e_+1], hza); hzb = __builtin_fmaf(hA.w, uzv[e_+1], hzb); \
      hra = __builtin_fmaf(hA.z, urv[e_+1], hra); hrb = __builtin_fmaf(hA.w, urv[e_+1], hrb); \
      hna = __builtin_fmaf(hA.z, uv.y,      hna); hnb = __builtin_fmaf(hA.w, uv.y,      hnb); \
      hza = __builtin_fmaf(hB.x, uzv[e_+2], hza); hzb = __builtin_fmaf(hB.y, uzv[e_+2], hzb); \
      hra = __builtin_fmaf(hB.x, urv[e_+2], hra); hrb = __builtin_fmaf(hB.y, urv[e_+2], hrb); \
      hna = __builtin_fmaf(hB.x, uv.z,      hna); hnb = __builtin_fmaf(hB.y, uv.z,      hnb); \
      hza = __builtin_fmaf(hB.z, uzv[e_+3], hza); hzb = __builtin_fmaf(hB.w, uzv[e_+3], hzb); \
      hra = __builtin_fmaf(hB.z, urv[e_+3], hra); hrb = __builtin_fmaf(hB.w, urv[e_+3], hrb); \
      hna = __builtin_fmaf(hB.z, uv.w,      hna); hnb = __builtin_fmaf(hB.w, uv.w,      hnb); }
#define DOTBLK(uzv, urv, blk) \
    DOTC(uzv, urv, blk, 0) DOTC(uzv, urv, blk, 1) DOTC(uzv, urv, blk, 2) DOTC(uzv, urv, blk, 3)
    DOTBLK(uz0, ur0, 0)
    DOTBLK(uz1, ur1, 1)
    DOTBLK(uz2, ur2, 2)
    DOTBLK(uz3, ur3, 3)
#undef DOTBLK
#undef DOTC
  }

  if (j == 0) {
    *(float2*)&out[NSAMP * NSTEP + s_base] = float2{logPa, logPb};
  }
}

extern "C" void kernel_launch(void* const* d_in, const int* in_sizes, int n_in,
                              void* d_out, int out_size, void* d_ws, size_t ws_size,
                              hipStream_t stream) {
  // inputs (setup_inputs order): nsamples(1), W(2x192), U(64x192), b(2x192),
  // Wd(64x2), bd(2) — float32
  const float* W  = (const float*)d_in[1];
  const float* U  = (const float*)d_in[2];
  const float* B  = (const float*)d_in[3];
  const float* Wd = (const float*)d_in[4];
  const float* Bd = (const float*)d_in[5];
  vmc_kernel<<<dim3(NSAMP / CPB), dim3(HID), 0, stream>>>(W, U, B, Wd, Bd, (float*)d_out);
}